// Round 1
// baseline (80.060 us; speedup 1.0000x reference)
//
#include <hip/hip_runtime.h>
#include <math.h>

// Problem constants: B=4, CIN=32, COUT=64, H=W=32, K=3, pad=1

typedef _Float16 half8 __attribute__((ext_vector_type(8)));
typedef _Float16 half4 __attribute__((ext_vector_type(4)));
typedef float floatx4 __attribute__((ext_vector_type(4)));

// ---------------- workspace layout ----------------
// B_f16: [var 2][tap 9][kchunk 16][n 128][16B]  = 576 KB (L2-resident)
//   n = xy*64 + o (xy: 0=cos-weights, 1=sin-weights)
//   kchunk q holds k = q*8 + j; c = k>>2 = q*2 + (j>>2), feat = k&3
//   var 0 = hi, var 1 = lo*2048
// COALESCED for the MFMA wave read (R12). B-lo required (R9: atan2 branch cut).
// FLAG at Bg + 1 MiB: in-kernel grid barrier counter (zeroed by memset node).
#define B_TAP_STRIDE (16 * 128 * 16)    // 32768
#define B_VSTRIDE (9u * 16 * 128 * 16)  // 294912
#define FLAG_OFF (1u << 20)

#define AL_OFF 26112  // 1632 * 16

#define BLOAD(dst, base)                     \
  do {                                       \
    dst##0 = *(const half8*)((base));        \
    dst##1 = *(const half8*)((base) + 8192); \
    dst##2 = *(const half8*)((base) + 16384);\
    dst##3 = *(const half8*)((base) + 24576);\
  } while (0)

// Fused single kernel (R13): prep_b distributed as 72 lanes/block (i = blk*72+tid,
// bit-identical values & layout to the old ring_prep_b), overlapped with A-setup;
// in-kernel grid flag-barrier replaces the serialized second launch.
// Co-residency: grid 256 == #CUs, 1 block/CU always fits (56 KB LDS, <=256 VGPR)
// -> every block resident -> flag barrier cannot deadlock. Poll uses atomicAdd(p,0)
// (RMW -> coherent point, no stale-L2 spin) and >=256 (rocprof replay-safe).
__global__ __launch_bounds__(512, 2) void ring_fused(
    const float* __restrict__ x, const float* __restrict__ probe,
    const float* __restrict__ outw, char* __restrict__ Bg,
    float* __restrict__ out) {
  __shared__ __align__(16) char sA[52224];
  __shared__ float sEx[1024];  // [wt 2][og 2][n 16][m 16]

  int blk = blockIdx.x;  // (b*32 + h)*2 + oh
  int oh = blk & 1;
  int h = (blk >> 1) & 31;
  int b = blk >> 6;
  int tid = threadIdx.x;

  // ---------------- B-prep share: lanes 0..71 (i in [0,18432)) ----------------
  if (tid < 72) {
    int i = blk * 72 + tid;
    int q = i & 15;
    int n = (i >> 4) & 127;
    int tap = i >> 11;
    int o = n & 63;
    int xy = n >> 6;
    half8 hi, lo;
#pragma unroll
    for (int hf = 0; hf < 2; ++hf) {
      int c = q * 2 + hf;
      int idx = (c * 64 + o) * 9 + tap;  // ((c*COUT + o)*3 + k)*3 + l
      float th = probe[idx];
      float wvv = outw[idx];
      float sth, cth, sw, cw;
      __sincosf(th, &sth, &cth);
      __sincosf(wvv, &sw, &cw);
      float c3 = cth * fmaf(4.0f * cth, cth, -3.0f);
      float s3 = sth * fmaf(-4.0f * sth, sth, 3.0f);
      float m = xy ? sw : cw;
      float v4[4] = {0.75f * m * cth, 0.75f * m * sth, 0.25f * m * c3,
                     0.25f * m * s3};
#pragma unroll
      for (int f = 0; f < 4; ++f) {
        _Float16 hv = (_Float16)v4[f];
        hi[hf * 4 + f] = hv;
        lo[hf * 4 + f] = (_Float16)((v4[f] - (float)hv) * 2048.0f);
      }
    }
    size_t off = (((size_t)tap * 16 + q) * 128 + n) * 16;
    *(half8*)(Bg + off) = hi;
    *(half8*)(Bg + off + B_VSTRIDE) = lo;
  }

  int lane = tid & 63;
  int wv = tid >> 6;
  int n16 = lane & 15;
  int quad = lane >> 4;
  int wt = wv >> 2;
  int xy = (wv >> 1) & 1;
  int og = wv & 1;

  // ---- A-setup, COALESCED producer mapping (R13): unit u = (r*32+c)*34 + col.
  // Consecutive lanes -> consecutive wsx within one (r,c) row of x: ~3 cache
  // lines per wave-load vs 64 with the old p-major XOR mapping. Stored LDS
  // layout is BYTE-IDENTICAL to before (XOR moved into the store address), so
  // the MFMA-side swizzled reads are unchanged.
  {
    float xv[7];
#pragma unroll
    for (int it = 0; it < 7; ++it) {
      int u = tid + it * 512;
      int colidx = u % 34;
      int t = u / 34;  // r*32 + c
      int c = t & 31;
      int r = t >> 5;
      int hs = h + r - 1;
      int wsx = colidx - 1;
      bool valid = (u < 3264) && ((unsigned)hs < 32u) && ((unsigned)wsx < 32u);
      int xi = ((b * 32 + c) * 32 + ((unsigned)hs < 32u ? hs : 0)) * 32 +
               ((unsigned)wsx < 32u ? wsx : 0);
      xv[it] = valid ? x[xi] : 0.0f;  // pad -> phase 0 -> (1,0,1,0)
    }
#pragma unroll
    for (int it = 0; it < 7; ++it) {
      int u = tid + it * 512;
      if (u < 3264) {
        int colidx = u % 34;
        int t = u / 34;
        int c = t & 31;
        int r = t >> 5;
        int q = c >> 1;
        int hf = c & 1;
        int p = q ^ (colidx & 7);  // same swizzle as the MFMA-side read
        float s1, c1;
        __sincosf(xv[it], &s1, &c1);
        float c3 = c1 * fmaf(4.0f * c1, c1, -3.0f);
        float s3 = s1 * fmaf(-4.0f * s1, s1, 3.0f);
        float v4[4] = {c1, s1, c3, s3};
        half4 hi4, lo4;
#pragma unroll
        for (int f = 0; f < 4; ++f) {
          _Float16 hv = (_Float16)v4[f];
          hi4[f] = hv;
          lo4[f] = (_Float16)((v4[f] - (float)hv) * 2048.0f);
        }
        int ub = ((r * 34 + colidx) * 16 + p) * 16 + hf * 8;
        *(half4*)(sA + ub) = hi4;            // var 0 (hi)
        *(half4*)(sA + ub + AL_OFF) = lo4;   // var 1 (lo*2048)
      }
    }
  }

  // ---- grid barrier: A-tile done locally; wait for all blocks' B shares ----
  __syncthreads();  // drains this block's global B stores (vmcnt0) + sA visible
  unsigned int* flag = (unsigned int*)(Bg + FLAG_OFF);
  if (tid == 0) {
    __threadfence();        // release: push this XCD's B lines device-visible
    atomicAdd(flag, 1u);
    while (atomicAdd(flag, 0u) < 256u) {  // RMW poll: always coherent
      __builtin_amdgcn_s_sleep(8);
    }
    __threadfence();        // acquire: invalidate stale B in this L1/L2
  }
  __syncthreads();

  int n_global = xy * 64 + oh * 32 + og * 16 + n16;
  const char* bLane = Bg + quad * 2048 + (size_t)n_global * 16;

  // ---- prefetch taps 0 and 1 (hi+lo) ----
  half8 BcH0, BcH1, BcH2, BcH3, BcL0, BcL1, BcL2, BcL3;  // tap t
  half8 BnH0, BnH1, BnH2, BnH3, BnL0, BnL1, BnL2, BnL3;  // tap t+1
  half8 BtH0, BtH1, BtH2, BtH3, BtL0, BtL1, BtL2, BtL3;  // tap t+2
  BLOAD(BcH, bLane);
  BLOAD(BcL, bLane + B_VSTRIDE);
  BLOAD(BnH, bLane + B_TAP_STRIDE);
  BLOAD(BnL, bLane + B_TAP_STRIDE + B_VSTRIDE);

  floatx4 acc0 = {0.f, 0.f, 0.f, 0.f};  // Ah*Bh
  floatx4 acc1 = {0.f, 0.f, 0.f, 0.f};  // Al*Bh
  floatx4 acc2 = {0.f, 0.f, 0.f, 0.f};  // Ah*Bl

#pragma unroll
  for (int tap = 0; tap < 9; ++tap) {
    // prefetch tap+2's B (hi+lo) into the third buffer
    if (tap < 7) {
      const char* bt = bLane + (size_t)(tap + 2) * B_TAP_STRIDE;
      BLOAD(BtH, bt);
      BLOAD(BtL, bt + B_VSTRIDE);
    }

    int dk = tap / 3;
    int l = tap - dk * 3;
    int colidx = wt * 16 + n16 + l;
    int akey = colidx & 7;
    const char* aH = sA + (dk * 34 + colidx) * 256;
    const char* aL = aH + AL_OFF;

#pragma unroll
    for (int ks = 0; ks < 4; ++ks) {
      int pa = ((ks * 4 + quad) ^ akey) * 16;
      half8 Ah = *(const half8*)(aH + pa);
      half8 Al = *(const half8*)(aL + pa);
      half8 Bh = (ks == 0) ? BcH0 : (ks == 1) ? BcH1 : (ks == 2) ? BcH2 : BcH3;
      half8 Bl = (ks == 0) ? BcL0 : (ks == 1) ? BcL1 : (ks == 2) ? BcL2 : BcL3;
      acc0 = __builtin_amdgcn_mfma_f32_16x16x32_f16(Ah, Bh, acc0, 0, 0, 0);
      acc1 = __builtin_amdgcn_mfma_f32_16x16x32_f16(Al, Bh, acc1, 0, 0, 0);
      acc2 = __builtin_amdgcn_mfma_f32_16x16x32_f16(Ah, Bl, acc2, 0, 0, 0);
    }
    // rotate the 3-stage pipeline (fully unrolled -> register renaming)
    BcH0 = BnH0; BcH1 = BnH1; BcH2 = BnH2; BcH3 = BnH3;
    BcL0 = BnL0; BcL1 = BnL1; BcL2 = BnL2; BcL3 = BnL3;
    BnH0 = BtH0; BnH1 = BtH1; BnH2 = BtH2; BnH3 = BtH3;
    BnL0 = BtL0; BnL1 = BtL1; BnL2 = BtL2; BnL3 = BtL3;
  }

  floatx4 fin = acc0 + (acc1 + acc2) * (1.0f / 2048.0f);

  // ---- epilogue: y-waves hand ay to x-waves (same wt,og); atan2 + store ----
  __syncthreads();
  if (xy == 1) {
#pragma unroll
    for (int r = 0; r < 4; ++r)
      sEx[((wt * 2 + og) * 16 + n16) * 16 + quad * 4 + r] = fin[r];
  }
  __syncthreads();
  if (xy == 0) {
    int o = oh * 32 + og * 16 + n16;
    float4 res;
    float* rp = (float*)&res;
#pragma unroll
    for (int r = 0; r < 4; ++r) {
      int m = quad * 4 + r;
      float ay = sEx[((wt * 2 + og) * 16 + n16) * 16 + m];
      rp[r] = atan2f(ay, fin[r]);
    }
    float* dst = out + (((size_t)(b * 64 + o) * 32 + h) * 32 + wt * 16 + quad * 4);
    *(float4*)dst = res;
  }
}

extern "C" void kernel_launch(void* const* d_in, const int* in_sizes, int n_in,
                              void* d_out, int out_size, void* d_ws, size_t ws_size,
                              hipStream_t stream) {
  const float* x = (const float*)d_in[0];
  const float* probe = (const float*)d_in[1];
  const float* outw = (const float*)d_in[2];
  char* Bg = (char*)d_ws;
  float* out = (float*)d_out;

  hipMemsetAsync(Bg + FLAG_OFF, 0, 4, stream);  // zero the barrier flag
  ring_fused<<<256, 512, 0, stream>>>(x, probe, outw, Bg, out);
}

// Round 2
// 66.874 us; speedup vs baseline: 1.1972x; 1.1972x over previous
//
#include <hip/hip_runtime.h>
#include <math.h>

// Problem constants: B=4, CIN=32, COUT=64, H=W=32, K=3, pad=1

typedef _Float16 half8 __attribute__((ext_vector_type(8)));
typedef _Float16 half4 __attribute__((ext_vector_type(4)));
typedef float floatx4 __attribute__((ext_vector_type(4)));

// ---------------- workspace layout ----------------
// B_f16: [var 2][tap 9][kchunk 16][n 128][16B]  = 576 KB (L2-resident)
//   n = xy*64 + o (xy: 0=cos-weights, 1=sin-weights)
//   kchunk q holds k = q*8 + j; c = k>>2 = q*2 + (j>>2), feat = k&3
//   var 0 = hi, var 1 = lo*2048
// COALESCED for the MFMA wave read (R12). B-lo required (R9: atan2 branch cut).
// R14: two-kernel structure RESTORED — R13's fused grid-barrier cost +12 us
// (device-scope fence = cross-XCD L2 writeback/inv + serialized RMW poll).
#define B_TAP_STRIDE (16 * 128 * 16)    // 32768
#define B_VSTRIDE (9u * 16 * 128 * 16)  // 294912

#define AL_OFF 26112  // 1632 * 16

__global__ __launch_bounds__(256) void ring_prep_b(
    const float* __restrict__ probe, const float* __restrict__ outw,
    char* __restrict__ Bg) {
  int i = blockIdx.x * 256 + threadIdx.x;  // 18432 threads = 72 blocks
  int q = i & 15;                          // kchunk (no XOR)
  int n = (i >> 4) & 127;
  int tap = i >> 11;
  int o = n & 63;
  int xy = n >> 6;
  half8 hi, lo;
#pragma unroll
  for (int hf = 0; hf < 2; ++hf) {
    int c = q * 2 + hf;
    int idx = (c * 64 + o) * 9 + tap;  // ((c*COUT + o)*3 + k)*3 + l
    float th = probe[idx];
    float wvv = outw[idx];
    float sth, cth, sw, cw;
    __sincosf(th, &sth, &cth);
    __sincosf(wvv, &sw, &cw);
    float c3 = cth * fmaf(4.0f * cth, cth, -3.0f);
    float s3 = sth * fmaf(-4.0f * sth, sth, 3.0f);
    float m = xy ? sw : cw;
    float v4[4] = {0.75f * m * cth, 0.75f * m * sth, 0.25f * m * c3,
                   0.25f * m * s3};
#pragma unroll
    for (int f = 0; f < 4; ++f) {
      _Float16 hv = (_Float16)v4[f];
      hi[hf * 4 + f] = hv;
      lo[hf * 4 + f] = (_Float16)((v4[f] - (float)hv) * 2048.0f);
    }
  }
  size_t off = (((size_t)tap * 16 + q) * 128 + n) * 16;
  *(half8*)(Bg + off) = hi;
  *(half8*)(Bg + off + B_VSTRIDE) = lo;
}

// R14 split-K wave roles: wave wv -> kg = wv>>2 (kchunk half), xy = (wv>>1)&1,
// og = wv&1. Each wave computes BOTH wt pixel-halves with its half of K:
// B global traffic per block HALVES (576 -> 288 KB, was the largest tap-loop
// term: per-XCD L2 BW), MFMA count (12/wave/tap), LDS A-read count
// (8 x ds_read_b128/wave/tap) and the XOR bank pattern are UNCHANGED.
// B register pipeline shrinks 96 -> 48 VGPRs. Epilogue: one extra LDS
// exchange (sR) sums over kg, then ay -> ax handoff for atan2.
#define BLOAD2(dst, base)                    \
  do {                                       \
    dst##0 = *(const half8*)((base));        \
    dst##1 = *(const half8*)((base) + 8192); \
  } while (0)

__global__ __launch_bounds__(512, 2) void ring_mfma(
    const float* __restrict__ x, const char* __restrict__ Bg,
    float* __restrict__ out) {
  __shared__ __align__(16) char sA[52224];
  __shared__ __align__(16) float sR[4096];  // [wv 8][wt 2][n16 16][m 16]

  int blk = blockIdx.x;  // (b*32 + h)*2 + oh
  int oh = blk & 1;
  int h = (blk >> 1) & 31;
  int b = blk >> 6;
  int tid = threadIdx.x;

  int lane = tid & 63;
  int wv = tid >> 6;
  int n16 = lane & 15;
  int quad = lane >> 4;
  int kg = wv >> 2;
  int xy = (wv >> 1) & 1;
  int og = wv & 1;

  int n_global = xy * 64 + oh * 32 + og * 16 + n16;
  // lane base: this wave's kchunks are kg*8 + {quad, quad+4}
  const char* bLane = Bg + (kg * 8 + quad) * 2048 + (size_t)n_global * 16;

  // ---- prefetch taps 0 and 1 (hi+lo) — in flight across the A-setup ----
  half8 BcH0, BcH1, BcL0, BcL1;  // tap t
  half8 BnH0, BnH1, BnL0, BnL1;  // tap t+1
  half8 BtH0, BtH1, BtL0, BtL1;  // tap t+2
  BLOAD2(BcH, bLane);
  BLOAD2(BcL, bLane + B_VSTRIDE);
  BLOAD2(BnH, bLane + B_TAP_STRIDE);
  BLOAD2(BnL, bLane + B_TAP_STRIDE + B_VSTRIDE);

  // ---- A-setup, COALESCED producer mapping (R13, proven correct): unit
  // u = (r*32+c)*34 + col; consecutive lanes -> consecutive wsx within one
  // (r,c) row of x (~3 cache lines/wave-load vs 64 p-major). Stored LDS
  // layout BYTE-IDENTICAL to the proven kernel (XOR moved into store addr).
  {
    float xv[7];
#pragma unroll
    for (int it = 0; it < 7; ++it) {
      int u = tid + it * 512;
      int colidx = u % 34;
      int t = u / 34;  // r*32 + c
      int c = t & 31;
      int r = t >> 5;
      int hs = h + r - 1;
      int wsx = colidx - 1;
      bool valid = (u < 3264) && ((unsigned)hs < 32u) && ((unsigned)wsx < 32u);
      int xi = ((b * 32 + c) * 32 + ((unsigned)hs < 32u ? hs : 0)) * 32 +
               ((unsigned)wsx < 32u ? wsx : 0);
      xv[it] = valid ? x[xi] : 0.0f;  // pad -> phase 0 -> (1,0,1,0)
    }
#pragma unroll
    for (int it = 0; it < 7; ++it) {
      int u = tid + it * 512;
      if (u < 3264) {
        int colidx = u % 34;
        int t = u / 34;
        int c = t & 31;
        int r = t >> 5;
        int q = c >> 1;
        int hf = c & 1;
        int p = q ^ (colidx & 7);  // same swizzle as the MFMA-side read
        float s1, c1;
        __sincosf(xv[it], &s1, &c1);
        float c3 = c1 * fmaf(4.0f * c1, c1, -3.0f);
        float s3 = s1 * fmaf(-4.0f * s1, s1, 3.0f);
        float v4[4] = {c1, s1, c3, s3};
        half4 hi4, lo4;
#pragma unroll
        for (int f = 0; f < 4; ++f) {
          _Float16 hv = (_Float16)v4[f];
          hi4[f] = hv;
          lo4[f] = (_Float16)((v4[f] - (float)hv) * 2048.0f);
        }
        int ub = ((r * 34 + colidx) * 16 + p) * 16 + hf * 8;
        *(half4*)(sA + ub) = hi4;           // var 0 (hi)
        *(half4*)(sA + ub + AL_OFF) = lo4;  // var 1 (lo*2048)
      }
    }
  }

  floatx4 acc0[2], acc1[2], acc2[2];
#pragma unroll
  for (int wt = 0; wt < 2; ++wt) {
    acc0[wt] = (floatx4){0.f, 0.f, 0.f, 0.f};  // Ah*Bh
    acc1[wt] = (floatx4){0.f, 0.f, 0.f, 0.f};  // Al*Bh
    acc2[wt] = (floatx4){0.f, 0.f, 0.f, 0.f};  // Ah*Bl
  }

  __syncthreads();  // A tile visible; tap loop is barrier-free

#pragma unroll
  for (int tap = 0; tap < 9; ++tap) {
    // prefetch tap+2's B (hi+lo) into the third buffer
    if (tap < 7) {
      const char* bt = bLane + (size_t)(tap + 2) * B_TAP_STRIDE;
      BLOAD2(BtH, bt);
      BLOAD2(BtL, bt + B_VSTRIDE);
    }

    int dk = tap / 3;
    int l = tap - dk * 3;
#pragma unroll
    for (int wt = 0; wt < 2; ++wt) {
      int colidx = wt * 16 + n16 + l;
      int akey = colidx & 7;  // same for both wt (16 % 8 == 0)
      const char* aH = sA + (dk * 34 + colidx) * 256;
      const char* aL = aH + AL_OFF;
#pragma unroll
      for (int ksl = 0; ksl < 2; ++ksl) {
        int chunk = (kg * 2 + ksl) * 4 + quad;
        int pa = (chunk ^ akey) * 16;
        half8 Ah = *(const half8*)(aH + pa);
        half8 Al = *(const half8*)(aL + pa);
        half8 Bh = ksl ? BcH1 : BcH0;
        half8 Bl = ksl ? BcL1 : BcL0;
        acc0[wt] = __builtin_amdgcn_mfma_f32_16x16x32_f16(Ah, Bh, acc0[wt], 0, 0, 0);
        acc1[wt] = __builtin_amdgcn_mfma_f32_16x16x32_f16(Al, Bh, acc1[wt], 0, 0, 0);
        acc2[wt] = __builtin_amdgcn_mfma_f32_16x16x32_f16(Ah, Bl, acc2[wt], 0, 0, 0);
      }
    }
    // rotate the 3-stage pipeline (fully unrolled -> register renaming)
    BcH0 = BnH0; BcH1 = BnH1; BcL0 = BnL0; BcL1 = BnL1;
    BnH0 = BtH0; BnH1 = BtH1; BnL0 = BtL0; BnL1 = BtL1;
  }

  floatx4 finA = acc0[0] + (acc1[0] + acc2[0]) * (1.0f / 2048.0f);  // wt=0
  floatx4 finB = acc0[1] + (acc1[1] + acc2[1]) * (1.0f / 2048.0f);  // wt=1

  // ---- epilogue: kg-sum + ay->ax handoff in one exchange ----
  // masters = waves wv<2 (kg=0, xy=0, og=wv); everyone else posts partials.
  // sR slot(wvi, wt): wvi*512 + wt*256 + n16*16 + quad*4 — sequential float4s.
  if (wv >= 2) {
    int basei = wv * 512 + n16 * 16 + quad * 4;
    *(floatx4*)(sR + basei) = finA;
    *(floatx4*)(sR + basei + 256) = finB;
  }
  __syncthreads();
  if (wv < 2) {
    int o = oh * 32 + og * 16 + n16;
#pragma unroll
    for (int wt = 0; wt < 2; ++wt) {
      floatx4 fin = wt ? finB : finA;
      int sb = wt * 256 + n16 * 16 + quad * 4;
      floatx4 axE = *(const floatx4*)(sR + (4 + og) * 512 + sb);  // kg1,xy0
      floatx4 ay1 = *(const floatx4*)(sR + (2 + og) * 512 + sb);  // kg0,xy1
      floatx4 ay2 = *(const floatx4*)(sR + (6 + og) * 512 + sb);  // kg1,xy1
      floatx4 ax4 = fin + axE;
      floatx4 ay4 = ay1 + ay2;
      float4 res;
      float* rp = (float*)&res;
#pragma unroll
      for (int r = 0; r < 4; ++r) rp[r] = atan2f(ay4[r], ax4[r]);
      float* dst =
          out + (((size_t)(b * 64 + o) * 32 + h) * 32 + wt * 16 + quad * 4);
      *(float4*)dst = res;
    }
  }
}

extern "C" void kernel_launch(void* const* d_in, const int* in_sizes, int n_in,
                              void* d_out, int out_size, void* d_ws, size_t ws_size,
                              hipStream_t stream) {
  const float* x = (const float*)d_in[0];
  const float* probe = (const float*)d_in[1];
  const float* outw = (const float*)d_in[2];
  char* Bg = (char*)d_ws;
  float* out = (float*)d_out;

  ring_prep_b<<<72, 256, 0, stream>>>(probe, outw, Bg);
  ring_mfma<<<256, 512, 0, stream>>>(x, Bg, out);
}

// Round 3
// 66.193 us; speedup vs baseline: 1.2095x; 1.0103x over previous
//
#include <hip/hip_runtime.h>
#include <math.h>

// Problem constants: B=4, CIN=32, COUT=64, H=W=32, K=3, pad=1

typedef _Float16 half8 __attribute__((ext_vector_type(8)));
typedef _Float16 half4 __attribute__((ext_vector_type(4)));
typedef float floatx4 __attribute__((ext_vector_type(4)));

// ---------------- workspace layout ----------------
// B_f16: [var 2][tap 9][kchunk 16][n 128][16B]  = 576 KB (L2-resident)
//   n = xy*64 + o (xy: 0=cos-weights, 1=sin-weights)
//   kchunk q holds k = q*8 + j; c = k>>2 = q*2 + (j>>2), feat = k&3
//   var 0 = hi, var 1 = lo*2048
// COALESCED for the MFMA wave read (R12). B-lo required (R9: atan2 branch cut).
// Two-kernel structure (R14): fused grid-barrier costs +12us (R13 failure:
// device-scope fences = cross-XCD L2 writeback/inv + serialized RMW poll).
#define B_TAP_STRIDE (16 * 128 * 16)    // 32768
#define B_VSTRIDE (9u * 16 * 128 * 16)  // 294912

#define AL_OFF 26112  // 1632 * 16

__global__ __launch_bounds__(256) void ring_prep_b(
    const float* __restrict__ probe, const float* __restrict__ outw,
    char* __restrict__ Bg) {
  int i = blockIdx.x * 256 + threadIdx.x;  // 18432 threads = 72 blocks
  int q = i & 15;                          // kchunk (no XOR)
  int n = (i >> 4) & 127;
  int tap = i >> 11;
  int o = n & 63;
  int xy = n >> 6;
  half8 hi, lo;
#pragma unroll
  for (int hf = 0; hf < 2; ++hf) {
    int c = q * 2 + hf;
    int idx = (c * 64 + o) * 9 + tap;  // ((c*COUT + o)*3 + k)*3 + l
    float th = probe[idx];
    float wvv = outw[idx];
    float sth, cth, sw, cw;
    __sincosf(th, &sth, &cth);
    __sincosf(wvv, &sw, &cw);
    float c3 = cth * fmaf(4.0f * cth, cth, -3.0f);
    float s3 = sth * fmaf(-4.0f * sth, sth, 3.0f);
    float m = xy ? sw : cw;
    float v4[4] = {0.75f * m * cth, 0.75f * m * sth, 0.25f * m * c3,
                   0.25f * m * s3};
#pragma unroll
    for (int f = 0; f < 4; ++f) {
      _Float16 hv = (_Float16)v4[f];
      hi[hf * 4 + f] = hv;
      lo[hf * 4 + f] = (_Float16)((v4[f] - (float)hv) * 2048.0f);
    }
  }
  size_t off = (((size_t)tap * 16 + q) * 128 + n) * 16;
  *(half8*)(Bg + off) = hi;
  *(half8*)(Bg + off + B_VSTRIDE) = lo;
}

// R14 split-K wave roles: wave wv -> kg = wv>>2, xy = (wv>>1)&1, og = wv&1.
// Each wave computes BOTH wt pixel-halves with its half of K (B traffic per
// block halved). R15: A-setup units merged to full-kchunk b128 stores (halve
// LDS store issues); epilogue distributed across all 512 threads.
#define BLOAD2(dst, base)                    \
  do {                                       \
    dst##0 = *(const half8*)((base));        \
    dst##1 = *(const half8*)((base) + 8192); \
  } while (0)

__global__ __launch_bounds__(512, 2) void ring_mfma(
    const float* __restrict__ x, const char* __restrict__ Bg,
    float* __restrict__ out) {
  __shared__ __align__(16) char sA[52224];
  __shared__ __align__(16) float sR[4096];  // [wv 8][wt 2][n16 16][m 16]

  int blk = blockIdx.x;  // (b*32 + h)*2 + oh
  int oh = blk & 1;
  int h = (blk >> 1) & 31;
  int b = blk >> 6;
  int tid = threadIdx.x;

  int lane = tid & 63;
  int wv = tid >> 6;
  int n16 = lane & 15;
  int quad = lane >> 4;
  int kg = wv >> 2;
  int xy = (wv >> 1) & 1;
  int og = wv & 1;

  int n_global = xy * 64 + oh * 32 + og * 16 + n16;
  // lane base: this wave's kchunks are kg*8 + {quad, quad+4}
  const char* bLane = Bg + (kg * 8 + quad) * 2048 + (size_t)n_global * 16;

  // ---- prefetch taps 0 and 1 (hi+lo) — in flight across the A-setup ----
  half8 BcH0, BcH1, BcL0, BcL1;  // tap t
  half8 BnH0, BnH1, BnL0, BnL1;  // tap t+1
  half8 BtH0, BtH1, BtL0, BtL1;  // tap t+2
  BLOAD2(BcH, bLane);
  BLOAD2(BcL, bLane + B_VSTRIDE);
  BLOAD2(BnH, bLane + B_TAP_STRIDE);
  BLOAD2(BnL, bLane + B_TAP_STRIDE + B_VSTRIDE);

  // ---- A-setup (R15): one unit = one (r, kchunk q, colidx) = BOTH hf halves,
  // stored as a single half8 per var -> 2 x ds_write_b128 (was 4 x b64), 4
  // iterations/thread (was 7). Gather stays colidx-fastest (coalesced along
  // w). Stored LDS bytes BYTE-IDENTICAL to the proven layout; MFMA-side
  // swizzled reads unchanged.
  {
    float xv0[4], xv1[4];
#pragma unroll
    for (int it = 0; it < 4; ++it) {
      int u = tid + it * 512;
      int colidx = u % 34;
      int t = u / 34;  // r*16 + q
      int q = t & 15;
      int r = t >> 4;
      int hs = h + r - 1;
      int wsx = colidx - 1;
      bool valid = (u < 1632) && ((unsigned)hs < 32u) && ((unsigned)wsx < 32u);
      int xi = ((b * 32 + q * 2) * 32 + ((unsigned)hs < 32u ? hs : 0)) * 32 +
               ((unsigned)wsx < 32u ? wsx : 0);
      xv0[it] = valid ? x[xi] : 0.0f;         // c = q*2   (pad -> phase 0)
      xv1[it] = valid ? x[xi + 1024] : 0.0f;  // c = q*2+1 (c stride = 32*32)
    }
#pragma unroll
    for (int it = 0; it < 4; ++it) {
      int u = tid + it * 512;
      if (u < 1632) {
        int colidx = u % 34;
        int t = u / 34;
        int q = t & 15;
        int r = t >> 4;
        int p = q ^ (colidx & 7);  // same swizzle as the MFMA-side read
        half8 hi, lo;
        float pv2[2] = {xv0[it], xv1[it]};
#pragma unroll
        for (int hf = 0; hf < 2; ++hf) {
          float s1, c1;
          __sincosf(pv2[hf], &s1, &c1);
          float c3 = c1 * fmaf(4.0f * c1, c1, -3.0f);
          float s3 = s1 * fmaf(-4.0f * s1, s1, 3.0f);
          float v4[4] = {c1, s1, c3, s3};
#pragma unroll
          for (int f = 0; f < 4; ++f) {
            _Float16 hv = (_Float16)v4[f];
            hi[hf * 4 + f] = hv;
            lo[hf * 4 + f] = (_Float16)((v4[f] - (float)hv) * 2048.0f);
          }
        }
        int ub = ((r * 34 + colidx) * 16 + p) * 16;
        *(half8*)(sA + ub) = hi;           // var 0 (hi)
        *(half8*)(sA + ub + AL_OFF) = lo;  // var 1 (lo*2048)
      }
    }
  }

  floatx4 acc0[2], acc1[2], acc2[2];
#pragma unroll
  for (int wt = 0; wt < 2; ++wt) {
    acc0[wt] = (floatx4){0.f, 0.f, 0.f, 0.f};  // Ah*Bh
    acc1[wt] = (floatx4){0.f, 0.f, 0.f, 0.f};  // Al*Bh
    acc2[wt] = (floatx4){0.f, 0.f, 0.f, 0.f};  // Ah*Bl
  }

  __syncthreads();  // A tile visible; tap loop is barrier-free

#pragma unroll
  for (int tap = 0; tap < 9; ++tap) {
    // prefetch tap+2's B (hi+lo) into the third buffer
    if (tap < 7) {
      const char* bt = bLane + (size_t)(tap + 2) * B_TAP_STRIDE;
      BLOAD2(BtH, bt);
      BLOAD2(BtL, bt + B_VSTRIDE);
    }

    int dk = tap / 3;
    int l = tap - dk * 3;
#pragma unroll
    for (int wt = 0; wt < 2; ++wt) {
      int colidx = wt * 16 + n16 + l;
      int akey = colidx & 7;  // same for both wt (16 % 8 == 0)
      const char* aH = sA + (dk * 34 + colidx) * 256;
      const char* aL = aH + AL_OFF;
#pragma unroll
      for (int ksl = 0; ksl < 2; ++ksl) {
        int chunk = (kg * 2 + ksl) * 4 + quad;
        int pa = (chunk ^ akey) * 16;
        half8 Ah = *(const half8*)(aH + pa);
        half8 Al = *(const half8*)(aL + pa);
        half8 Bh = ksl ? BcH1 : BcH0;
        half8 Bl = ksl ? BcL1 : BcL0;
        acc0[wt] = __builtin_amdgcn_mfma_f32_16x16x32_f16(Ah, Bh, acc0[wt], 0, 0, 0);
        acc1[wt] = __builtin_amdgcn_mfma_f32_16x16x32_f16(Al, Bh, acc1[wt], 0, 0, 0);
        acc2[wt] = __builtin_amdgcn_mfma_f32_16x16x32_f16(Ah, Bl, acc2[wt], 0, 0, 0);
      }
    }
    // rotate the 3-stage pipeline (fully unrolled -> register renaming)
    BcH0 = BnH0; BcH1 = BnH1; BcL0 = BnL0; BcL1 = BnL1;
    BnH0 = BtH0; BnH1 = BtH1; BnL0 = BtL0; BnL1 = BtL1;
  }

  floatx4 finA = acc0[0] + (acc1[0] + acc2[0]) * (1.0f / 2048.0f);  // wt=0
  floatx4 finB = acc0[1] + (acc1[1] + acc2[1]) * (1.0f / 2048.0f);  // wt=1

  // ---- epilogue (R15): all 8 waves post partials; 256 threads then each do
  // the kg-sum + ay/ax combine + 4 atan2 + one coalesced float4 store.
  // sR slot(wvi, wt): wvi*512 + wt*256 + n16*16 + quad*4 — sequential float4s.
  {
    int basei = wv * 512 + n16 * 16 + quad * 4;
    *(floatx4*)(sR + basei) = finA;
    *(floatx4*)(sR + basei + 256) = finB;
  }
  __syncthreads();
  if (tid < 256) {
    int o5 = tid >> 3;        // 0..31: o within this oh half
    int wt = (tid >> 2) & 1;  // pixel half
    int q4 = tid & 3;         // m quad
    int n16r = o5 & 15;
    int ogr = o5 >> 4;
    int sb = wt * 256 + n16r * 16 + q4 * 4;
    floatx4 ax4 = *(const floatx4*)(sR + (0 + ogr) * 512 + sb) +   // kg0,xy0
                  *(const floatx4*)(sR + (4 + ogr) * 512 + sb);    // kg1,xy0
    floatx4 ay4 = *(const floatx4*)(sR + (2 + ogr) * 512 + sb) +   // kg0,xy1
                  *(const floatx4*)(sR + (6 + ogr) * 512 + sb);    // kg1,xy1
    float4 res;
    float* rp = (float*)&res;
#pragma unroll
    for (int r = 0; r < 4; ++r) rp[r] = atan2f(ay4[r], ax4[r]);
    int o = oh * 32 + o5;
    float* dst =
        out + (((size_t)(b * 64 + o) * 32 + h) * 32 + wt * 16 + q4 * 4);
    *(float4*)dst = res;
  }
}

extern "C" void kernel_launch(void* const* d_in, const int* in_sizes, int n_in,
                              void* d_out, int out_size, void* d_ws, size_t ws_size,
                              hipStream_t stream) {
  const float* x = (const float*)d_in[0];
  const float* probe = (const float*)d_in[1];
  const float* outw = (const float*)d_in[2];
  char* Bg = (char*)d_ws;
  float* out = (float*)d_out;

  ring_prep_b<<<72, 256, 0, stream>>>(probe, outw, Bg);
  ring_mfma<<<256, 512, 0, stream>>>(x, Bg, out);
}